// Round 4
// baseline (197.783 us; speedup 1.0000x reference)
//
#include <hip/hip_runtime.h>
#include <hip/hip_bf16.h>

// EdgeDecoder: out[e] = w2 . relu(W1 @ concat(z_sotu[row[e]], z_taxon[col[e]]) + b1) + b2
// E=1e6, H=128, K=2H=256. fp32 inputs, int32 indices, fp32 output.
//
// Round 13 (diagnostic split + prep barrier reduction):
//  R12 post-mortem: edge ILP 4->8 NEUTRAL at half occupancy => edge is at a
//  ~3.5 TB/s random-line L3 service wall (FETCH-invariant 226 MB). Revert to
//  ILP=4 (65.3 us measured). Remaining unknown: prep ~= 45 us by subtraction
//  vs 18 us roofline, but never visible in top-5.
//  This round:
//   (a) edge split into 4 quarter-launches (~16.5 us each, L2 stays warm,
//       FETCH sum unchanged) -> prep's true dur_us becomes visible in top-5.
//   (b) prep: third LDS buffer (EB) for the epilogue -> 2 barriers/tile
//       instead of 3; epilogue writes a disjoint buffer so no drain between
//       MFMA reads of zl[p] and epilogue writes.
//  Predict: prep visible at ~38-43 us; 4x edge ~16.5 us; total ~186-188.

#define HID  128
#define FTE  128    // fallback tile
#define PST  136    // prep LDS row stride (bf16): 128 + 8 pad (272 B, 16B-aligned)
#define PTR  32     // prep tile rows
#define GU   1024   // prep blocks owning U (sotu) tiles
#define GT   512    // prep blocks owning V (taxon) tiles

typedef __attribute__((ext_vector_type(8)))  short    bf16x8;   // 8 bf16 = 4 VGPRs
typedef __attribute__((ext_vector_type(16))) float    f32x16;   // 32x32 MFMA accumulator
typedef __attribute__((ext_vector_type(4)))  unsigned uint4v;   // 16 B

__device__ __forceinline__ float bf2f(unsigned short u) {
    return __uint_as_float(((unsigned)u) << 16);
}
__device__ __forceinline__ unsigned pk2(float x, float y) {
    __hip_bfloat162 t = __float22bfloat162_rn(make_float2(x, y));  // packed RNE cvt
    return *reinterpret_cast<unsigned*>(&t);
}
__device__ __forceinline__ bf16x8 pack8(float4 a, float4 b) {
    uint4v r;
    r.x = pk2(a.x, a.y); r.y = pk2(a.z, a.w);
    r.z = pk2(b.x, b.y); r.w = pk2(b.z, b.w);
    return *reinterpret_cast<bf16x8*>(&r);
}

// ---------------- Phase 0: permute W1 into per-(half,wave,lane) fragment order.
// WF[((h*4+w)*64 + lane)*64 + ks*8 + j] = bf16(w1[(32w + (lane&31))*256
//                                         + h*128 + (lane>>5)*8 + ks*16 + j])
// Each prep lane then reads its 8 frags from its OWN contiguous 128 B line.
__global__ __launch_bounds__(256)
void w1prep_kernel(const float* __restrict__ w1, unsigned short* __restrict__ WF)
{
    const int tau = blockIdx.x * 256 + threadIdx.x;   // [0, 4096)
    const int ks  = tau & 7;
    const int lc  = tau >> 3;                          // lanecombo [0, 512)
    const int h   = lc >> 8;
    const int w   = (lc >> 6) & 3;
    const int ln  = lc & 63;
    const int l31 = ln & 31;
    const int hlf = ln >> 5;
    const float* src = w1 + (32 * w + l31) * 256 + h * 128 + hlf * 8 + ks * 16;
    const float4 a = *(const float4*)(src);
    const float4 b = *(const float4*)(src + 4);
    *(bf16x8*)(WF + lc * 64 + ks * 8) = pack8(a, b);
}

// ---------------- Phase 1: U = zs@W1s^T + b1, V = zt@W1t^T  (bf16 out, row-major)
// Persistent blocks; split-stage double buffer; EB epilogue buffer (2 barriers/tile).
__global__ __launch_bounds__(256)
void prep_kernel(const float* __restrict__ zs, const float* __restrict__ zt,
                 const unsigned short* __restrict__ WF, const float* __restrict__ b1,
                 unsigned short* __restrict__ U, unsigned short* __restrict__ V,
                 int NS, int NT)
{
    __shared__ __align__(16) unsigned short zl[2][PTR * PST];   // 2 x 8.7 KB staging
    __shared__ __align__(16) unsigned short EB[PTR * PST];      // epilogue transpose buf

    const bool isU = (int)blockIdx.x < GU;
    const float* z      = isU ? zs : zt;
    unsigned short* O   = isU ? U  : V;
    const int N    = isU ? NS : NT;
    const int nT   = (N + PTR - 1) / PTR;            // tiles in this region
    const int t0   = isU ? blockIdx.x : blockIdx.x - GU;
    const int step = isU ? GU : GT;

    const int tid  = threadIdx.x;
    const int wave = tid >> 6;       // hidden group: rows [32*wave, 32*wave+32)
    const int lane = tid & 63;
    const int l31  = lane & 31;
    const int hlf  = lane >> 5;

    if (t0 >= nT) return;

    // Per-thread staging regs: 2 x (row, chunk) covering the 32x128 fp32 tile.
    float4 ra[4];   // statically indexed only (unrolled) — stays in VGPRs

    auto stage_load = [&](int t) {
        #pragma unroll
        for (int i = 0; i < 2; ++i) {
            const int f = i * 256 + tid;
            const int r = f >> 4;
            const int c = f & 15;
            int s = t * PTR + r;
            if (s >= N) s = N - 1;                  // clamp (store guarded)
            const float* src = z + (long long)s * HID + c * 8;
            ra[2*i]     = *(const float4*)(src);
            ra[2*i + 1] = *(const float4*)(src + 4);
        }
    };
    auto stage_write = [&](unsigned short* buf) {
        #pragma unroll
        for (int i = 0; i < 2; ++i) {
            const int f = i * 256 + tid;
            const int r = f >> 4;
            const int c = f & 15;
            *(bf16x8*)(buf + r * PST + c * 8) = pack8(ra[2*i], ra[2*i + 1]);
        }
    };

    // First tile: issue loads; afrag/b1 loads overlap the staging latency.
    stage_load(t0);

    // A-frags: 8 x 16 B from this lane's own 128 B line of WF (coalesced, L2-hot).
    bf16x8 afrag[8];
    {
        const unsigned short* wfb = WF + ((((isU ? 0 : 4) + wave) * 64) + lane) * 64;
        #pragma unroll
        for (int ks = 0; ks < 8; ++ks)
            afrag[ks] = *(const bf16x8*)(wfb + ks * 8);
    }
    // b1 (U only): lane's 16 hidden = 32w + (reg&3) + 8*(reg>>2) + 4*hlf
    float b1v[16];
    #pragma unroll
    for (int g = 0; g < 4; ++g) {
        const int hb = 32 * wave + 8 * g + 4 * hlf;
        if (isU) {
            const float4 bb = *(const float4*)(b1 + hb);
            b1v[4*g+0] = bb.x; b1v[4*g+1] = bb.y; b1v[4*g+2] = bb.z; b1v[4*g+3] = bb.w;
        } else {
            b1v[4*g+0] = b1v[4*g+1] = b1v[4*g+2] = b1v[4*g+3] = 0.0f;
        }
    }
    stage_write(zl[0]);
    __syncthreads();

    int p = 0;
    for (int t = t0; t < nT; ) {
        const int tn = t + step;
        const bool pf = (tn < nT);

        // (1) issue-early: next tile's global loads go in flight now (no wait).
        if (pf) stage_load(tn);

        // (2) compute tile t: 8 MFMAs; B[n=l31][k=hlf*8+j] from LDS row l31.
        f32x16 acc = {};
        #pragma unroll
        for (int ks = 0; ks < 8; ++ks) {
            const bf16x8 bfrag = *(const bf16x8*)(zl[p] + l31 * PST + (2 * ks + hlf) * 8);
            acc = __builtin_amdgcn_mfma_f32_32x32x16_bf16(afrag[ks], bfrag, acc, 0, 0, 0);
        }

        // (3) epilogue transpose into EB — disjoint from zl[p], no barrier needed.
        //     Waves write disjoint 64 B column chunks of rows l31.
        #pragma unroll
        for (int g = 0; g < 4; ++g) {
            const int cb = 32 * wave + 8 * g + 4 * hlf;
            uint2 o;
            o.x = pk2(acc[4*g+0] + b1v[4*g+0], acc[4*g+1] + b1v[4*g+1]);
            o.y = pk2(acc[4*g+2] + b1v[4*g+2], acc[4*g+3] + b1v[4*g+3]);
            *(uint2*)(EB + l31 * PST + cb) = o;
        }
        __syncthreads();   // B1: EB writes visible (prev EB readers done via prev B2)

        // (4) coalesced store: 16 consecutive lanes emit one 256 B output row.
        #pragma unroll
        for (int i = 0; i < 2; ++i) {
            const int f = i * 256 + tid;
            const int r = f >> 4;
            const int c = f & 15;
            const int s2 = t * PTR + r;
            if (s2 < N)
                *(uint4v*)(O + (long long)s2 * HID + c * 8) =
                    *(const uint4v*)(EB + r * PST + c * 8);
        }

        // (5) write-late staging: vmcnt wait covers only residual latency.
        if (pf) stage_write(zl[p ^ 1]);

        __syncthreads();   // B2: zl[p^1] staged; EB reads done before next epilogue
        p ^= 1;
        t = tn;
    }
}

// ---------------- Phase 2: out[e] = w2 . relu(U[row[e]] + V[col[e]]) + b2
// 16 lanes/edge-group, 4 edges per group (8 gathers of 16 B in flight/thread).
// e_base allows quarter-grid launches (diagnostic split; L2 stays warm).
__global__ __launch_bounds__(256)
void edge_kernel(const unsigned short* __restrict__ U,   // [NS,128] bf16
                 const unsigned short* __restrict__ V,   // [NT,128] bf16
                 const int*   __restrict__ row, const int* __restrict__ col,
                 const float* __restrict__ w2, const float* __restrict__ b2,
                 float* __restrict__ out, int e_base, int E)
{
    const int tid = threadIdx.x;
    const int g   = tid >> 4;        // group 0..15
    const int c16 = tid & 15;        // channel chunk (8 channels)

    const long long eb = (long long)e_base + (long long)blockIdx.x * 64 + g * 4;

    int ri[4], ci[4];
    #pragma unroll
    for (int j = 0; j < 4; ++j) {
        long long e = eb + j;
        if (e >= E) e = E - 1;
        ri[j] = row[e]; ci[j] = col[e];
    }
    bf16x8 u[4], v[4];
    #pragma unroll
    for (int j = 0; j < 4; ++j) {
        u[j] = *(const bf16x8*)(U + (long long)ri[j] * HID + c16 * 8);
        v[j] = *(const bf16x8*)(V + (long long)ci[j] * HID + c16 * 8);
    }

    const float4 wa = *(const float4*)(w2 + c16 * 8);
    const float4 wb = *(const float4*)(w2 + c16 * 8 + 4);
    const float w2v[8] = {wa.x, wa.y, wa.z, wa.w, wb.x, wb.y, wb.z, wb.w};

    float p[4] = {0.0f, 0.0f, 0.0f, 0.0f};
    #pragma unroll
    for (int j = 0; j < 4; ++j) {
        #pragma unroll
        for (int k = 0; k < 8; ++k) {
            const float h = fmaxf(bf2f((unsigned short)u[j][k]) +
                                  bf2f((unsigned short)v[j][k]), 0.0f);
            p[j] = fmaf(h, w2v[k], p[j]);
        }
    }
    #pragma unroll
    for (int d = 1; d < 16; d <<= 1) {
        #pragma unroll
        for (int j = 0; j < 4; ++j) p[j] += __shfl_xor(p[j], d, 64);
    }
    if (c16 == 0) {
        const float bb = b2[0];
        if (eb + 3 < E) {
            *(float4*)(out + eb) = make_float4(p[0] + bb, p[1] + bb, p[2] + bb, p[3] + bb);
        } else {
            #pragma unroll
            for (int j = 0; j < 4; ++j)
                if (eb + j < E) out[eb + j] = p[j] + bb;
        }
    }
}

// ---------------- Fallback: round-2 proven fused kernel (only if ws too small)
__global__ __launch_bounds__(256, 2)
void edge_mlp_fused(const float* __restrict__ z_sotu, const float* __restrict__ z_taxon,
                    const int* __restrict__ row, const int* __restrict__ col,
                    const float* __restrict__ w1, const float* __restrict__ b1,
                    const float* __restrict__ w2, const float* __restrict__ b2,
                    float* __restrict__ out, int E)
{
    __shared__ __align__(16) unsigned short zsh[FTE * 256];
    const int tid  = threadIdx.x;
    const int wave = tid >> 6;
    const int lane = tid & 63;
    const int l31  = lane & 31;
    const int hlf  = lane >> 5;
    const long long e0 = (long long)blockIdx.x * FTE;
    {
        const int ch  = lane & 15;
        const int rhl = lane >> 4;
        #pragma unroll
        for (int pass = 0; pass < 16; ++pass) {
            const int rh = pass * 4 + rhl;
            const int r  = 32 * wave + (rh >> 1);
            const int hh = rh & 1;
            long long e = e0 + r;
            if (e >= E) e = E - 1;
            const int idx = hh ? col[e] : row[e];
            const float* src = (hh ? z_taxon : z_sotu) + (long long)idx * HID + ch * 8;
            const float4 a = *(const float4*)(src);
            const float4 b = *(const float4*)(src + 4);
            const int c = hh * 16 + ch;
            const int q = c ^ (r & 31);
            *(bf16x8*)(zsh + r * 256 + q * 8) = pack8(a, b);
        }
    }
    bf16x8 afrag[16];
    {
        const float* wrow = w1 + (32 * wave + l31) * 256 + hlf * 8;
        #pragma unroll
        for (int ks = 0; ks < 16; ++ks) {
            const float4 a = *(const float4*)(wrow + ks * 16);
            const float4 b = *(const float4*)(wrow + ks * 16 + 4);
            afrag[ks] = pack8(a, b);
        }
    }
    __syncthreads();
    f32x16 acc[4] = {};
    #pragma unroll
    for (int ks = 0; ks < 16; ++ks) {
        #pragma unroll
        for (int nt = 0; nt < 4; ++nt) {
            const int el = 32 * nt + l31;
            const int q  = (2 * ks + hlf) ^ l31;
            bf16x8 bfrag = *(const bf16x8*)(zsh + el * 256 + q * 8);
            acc[nt] = __builtin_amdgcn_mfma_f32_32x32x16_bf16(afrag[ks], bfrag, acc[nt], 0, 0, 0);
        }
    }
    __syncthreads();
    float* partial = (float*)zsh;
    float b1v[16], w2v[16];
    #pragma unroll
    for (int g = 0; g < 4; ++g) {
        const int hb = 32 * wave + 8 * g + 4 * hlf;
        const float4 bb = *(const float4*)(b1 + hb);
        const float4 ww = *(const float4*)(w2 + hb);
        b1v[4*g+0] = bb.x; b1v[4*g+1] = bb.y; b1v[4*g+2] = bb.z; b1v[4*g+3] = bb.w;
        w2v[4*g+0] = ww.x; w2v[4*g+1] = ww.y; w2v[4*g+2] = ww.z; w2v[4*g+3] = ww.w;
    }
    #pragma unroll
    for (int nt = 0; nt < 4; ++nt) {
        float p = 0.0f;
        #pragma unroll
        for (int r = 0; r < 16; ++r) {
            const float h = fmaxf(acc[nt][r] + b1v[r], 0.0f);
            p = fmaf(h, w2v[r], p);
        }
        p += __shfl_xor(p, 32, 64);
        if (hlf == 0)
            partial[wave * FTE + 32 * nt + l31] = p;
    }
    __syncthreads();
    if (tid < FTE) {
        const long long e = e0 + tid;
        if (e < E) {
            out[e] = partial[0 * FTE + tid] + partial[1 * FTE + tid]
                   + partial[2 * FTE + tid] + partial[3 * FTE + tid]
                   + b2[0];
        }
    }
}

extern "C" void kernel_launch(void* const* d_in, const int* in_sizes, int n_in,
                              void* d_out, int out_size, void* d_ws, size_t ws_size,
                              hipStream_t stream) {
    const float* z_sotu  = (const float*)d_in[0];
    const float* z_taxon = (const float*)d_in[1];
    const int*   row     = (const int*)d_in[2];
    const int*   col     = (const int*)d_in[3];
    const float* w1      = (const float*)d_in[4];
    const float* b1      = (const float*)d_in[5];
    const float* w2      = (const float*)d_in[6];
    const float* b2      = (const float*)d_in[7];
    float*       out     = (float*)d_out;

    const int NS = in_sizes[0] / HID;   // 100000
    const int NT = in_sizes[1] / HID;   //  50000
    const int E  = in_sizes[2];
    // U (25.6 MB) + V (12.8 MB) + WF fragment buffer (64 KB)
    const size_t need = ((size_t)NS + NT) * HID * 2 + 65536;

    if (ws_size >= need) {
        unsigned short* U  = (unsigned short*)d_ws;
        unsigned short* Vv = U + (size_t)NS * HID;
        unsigned short* WF = Vv + (size_t)NT * HID;
        hipLaunchKernelGGL(w1prep_kernel, dim3(16), dim3(256), 0, stream, w1, WF);
        hipLaunchKernelGGL(prep_kernel, dim3(GU + GT), dim3(256), 0, stream,
                           z_sotu, z_taxon, WF, b1, U, Vv, NS, NT);
        // Diagnostic split: 4 quarter-launches (prep becomes visible in top-5;
        // L2 stays warm between quarters, FETCH sum unchanged).
        const int nLaunch = 4;
        const long long chunk = ((((long long)E + nLaunch - 1) / nLaunch) + 63) / 64 * 64;
        for (int q = 0; q < nLaunch; ++q) {
            const long long base = (long long)q * chunk;
            if (base >= E) break;
            long long cnt = (long long)E - base;
            if (cnt > chunk) cnt = chunk;
            const int nb = (int)((cnt + 63) / 64);
            hipLaunchKernelGGL(edge_kernel, dim3(nb), dim3(256), 0, stream,
                               U, Vv, row, col, w2, b2, out, (int)base, E);
        }
    } else {
        const int nblocks = (E + FTE - 1) / FTE;
        hipLaunchKernelGGL(edge_mlp_fused, dim3(nblocks), dim3(256), 0, stream,
                           z_sotu, z_taxon, row, col, w1, b1, w2, b2, out, E);
    }
}

// Round 6
// 188.568 us; speedup vs baseline: 1.0489x; 1.0489x over previous
//
#include <hip/hip_runtime.h>
#include <hip/hip_bf16.h>

// EdgeDecoder: out[e] = w2 . relu(W1 @ concat(z_sotu[row[e]], z_taxon[col[e]]) + b1) + b2
// E=1e6, H=128, K=2H=256. fp32 inputs, int32 indices, fp32 output.
//
// Round 15 = Round 14 resubmit (R14 bench was an infra failure, container
// died twice; no data). Isolated A/B of EB epilogue buffer vs R11's 190.5:
//  R13 post-mortem: 4-way edge split REGRESSED +7.3 us (launch overhead +
//  lost head/tail overlap) but revealed: (a) harness re-poison fill of the
//  256 MB ws = 40.5 us/iter INSIDE the timed region (top-5 was all
//  fillBufferAligned); (b) prep < 40.3 us, and with R8's one-shot==persistent
//  result, prep is ~20-25 us vs 18.3 us streaming roofline. Fixed overhead
//  (fill + reset dispatches + gaps) ~= 95-110 us. Edge = 65.3 us service
//  wall (R12 falsified concurrency; FETCH-invariant 226 MB @ ~3.5 TB/s).
//  This round: single edge launch ILP=4 (R11-proven), keep EB 2-barrier
//  prep. Only diff vs R11 = EB => clean isolated A/B of EB.
//  Predict: total 188.5-190.5; top-5 = edge x5 @ ~65.3, FETCH ~225.5 MB.

#define HID  128
#define FTE  128    // fallback tile
#define PST  136    // prep LDS row stride (bf16): 128 + 8 pad (272 B, 16B-aligned)
#define PTR  32     // prep tile rows
#define GU   1024   // prep blocks owning U (sotu) tiles
#define GT   512    // prep blocks owning V (taxon) tiles

typedef __attribute__((ext_vector_type(8)))  short    bf16x8;   // 8 bf16 = 4 VGPRs
typedef __attribute__((ext_vector_type(16))) float    f32x16;   // 32x32 MFMA accumulator
typedef __attribute__((ext_vector_type(4)))  unsigned uint4v;   // 16 B

__device__ __forceinline__ float bf2f(unsigned short u) {
    return __uint_as_float(((unsigned)u) << 16);
}
__device__ __forceinline__ unsigned pk2(float x, float y) {
    __hip_bfloat162 t = __float22bfloat162_rn(make_float2(x, y));  // packed RNE cvt
    return *reinterpret_cast<unsigned*>(&t);
}
__device__ __forceinline__ bf16x8 pack8(float4 a, float4 b) {
    uint4v r;
    r.x = pk2(a.x, a.y); r.y = pk2(a.z, a.w);
    r.z = pk2(b.x, b.y); r.w = pk2(b.z, b.w);
    return *reinterpret_cast<bf16x8*>(&r);
}

// ---------------- Phase 0: permute W1 into per-(half,wave,lane) fragment order.
// WF[((h*4+w)*64 + lane)*64 + ks*8 + j] = bf16(w1[(32w + (lane&31))*256
//                                         + h*128 + (lane>>5)*8 + ks*16 + j])
// Each prep lane then reads its 8 frags from its OWN contiguous 128 B line.
__global__ __launch_bounds__(256)
void w1prep_kernel(const float* __restrict__ w1, unsigned short* __restrict__ WF)
{
    const int tau = blockIdx.x * 256 + threadIdx.x;   // [0, 4096)
    const int ks  = tau & 7;
    const int lc  = tau >> 3;                          // lanecombo [0, 512)
    const int h   = lc >> 8;
    const int w   = (lc >> 6) & 3;
    const int ln  = lc & 63;
    const int l31 = ln & 31;
    const int hlf = ln >> 5;
    const float* src = w1 + (32 * w + l31) * 256 + h * 128 + hlf * 8 + ks * 16;
    const float4 a = *(const float4*)(src);
    const float4 b = *(const float4*)(src + 4);
    *(bf16x8*)(WF + lc * 64 + ks * 8) = pack8(a, b);
}

// ---------------- Phase 1: U = zs@W1s^T + b1, V = zt@W1t^T  (bf16 out, row-major)
// Persistent blocks; split-stage double buffer; EB epilogue buffer (2 barriers/tile).
__global__ __launch_bounds__(256)
void prep_kernel(const float* __restrict__ zs, const float* __restrict__ zt,
                 const unsigned short* __restrict__ WF, const float* __restrict__ b1,
                 unsigned short* __restrict__ U, unsigned short* __restrict__ V,
                 int NS, int NT)
{
    __shared__ __align__(16) unsigned short zl[2][PTR * PST];   // 2 x 8.7 KB staging
    __shared__ __align__(16) unsigned short EB[PTR * PST];      // epilogue transpose buf

    const bool isU = (int)blockIdx.x < GU;
    const float* z      = isU ? zs : zt;
    unsigned short* O   = isU ? U  : V;
    const int N    = isU ? NS : NT;
    const int nT   = (N + PTR - 1) / PTR;            // tiles in this region
    const int t0   = isU ? blockIdx.x : blockIdx.x - GU;
    const int step = isU ? GU : GT;

    const int tid  = threadIdx.x;
    const int wave = tid >> 6;       // hidden group: rows [32*wave, 32*wave+32)
    const int lane = tid & 63;
    const int l31  = lane & 31;
    const int hlf  = lane >> 5;

    if (t0 >= nT) return;

    // Per-thread staging regs: 2 x (row, chunk) covering the 32x128 fp32 tile.
    float4 ra[4];   // statically indexed only (unrolled) — stays in VGPRs

    auto stage_load = [&](int t) {
        #pragma unroll
        for (int i = 0; i < 2; ++i) {
            const int f = i * 256 + tid;
            const int r = f >> 4;
            const int c = f & 15;
            int s = t * PTR + r;
            if (s >= N) s = N - 1;                  // clamp (store guarded)
            const float* src = z + (long long)s * HID + c * 8;
            ra[2*i]     = *(const float4*)(src);
            ra[2*i + 1] = *(const float4*)(src + 4);
        }
    };
    auto stage_write = [&](unsigned short* buf) {
        #pragma unroll
        for (int i = 0; i < 2; ++i) {
            const int f = i * 256 + tid;
            const int r = f >> 4;
            const int c = f & 15;
            *(bf16x8*)(buf + r * PST + c * 8) = pack8(ra[2*i], ra[2*i + 1]);
        }
    };

    // First tile: issue loads; afrag/b1 loads overlap the staging latency.
    stage_load(t0);

    // A-frags: 8 x 16 B from this lane's own 128 B line of WF (coalesced, L2-hot).
    bf16x8 afrag[8];
    {
        const unsigned short* wfb = WF + ((((isU ? 0 : 4) + wave) * 64) + lane) * 64;
        #pragma unroll
        for (int ks = 0; ks < 8; ++ks)
            afrag[ks] = *(const bf16x8*)(wfb + ks * 8);
    }
    // b1 (U only): lane's 16 hidden = 32w + (reg&3) + 8*(reg>>2) + 4*hlf
    float b1v[16];
    #pragma unroll
    for (int g = 0; g < 4; ++g) {
        const int hb = 32 * wave + 8 * g + 4 * hlf;
        if (isU) {
            const float4 bb = *(const float4*)(b1 + hb);
            b1v[4*g+0] = bb.x; b1v[4*g+1] = bb.y; b1v[4*g+2] = bb.z; b1v[4*g+3] = bb.w;
        } else {
            b1v[4*g+0] = b1v[4*g+1] = b1v[4*g+2] = b1v[4*g+3] = 0.0f;
        }
    }
    stage_write(zl[0]);
    __syncthreads();

    int p = 0;
    for (int t = t0; t < nT; ) {
        const int tn = t + step;
        const bool pf = (tn < nT);

        // (1) issue-early: next tile's global loads go in flight now (no wait).
        if (pf) stage_load(tn);

        // (2) compute tile t: 8 MFMAs; B[n=l31][k=hlf*8+j] from LDS row l31.
        f32x16 acc = {};
        #pragma unroll
        for (int ks = 0; ks < 8; ++ks) {
            const bf16x8 bfrag = *(const bf16x8*)(zl[p] + l31 * PST + (2 * ks + hlf) * 8);
            acc = __builtin_amdgcn_mfma_f32_32x32x16_bf16(afrag[ks], bfrag, acc, 0, 0, 0);
        }

        // (3) epilogue transpose into EB — disjoint from zl[p], no barrier needed.
        //     Waves write disjoint 64 B column chunks of rows l31.
        #pragma unroll
        for (int g = 0; g < 4; ++g) {
            const int cb = 32 * wave + 8 * g + 4 * hlf;
            uint2 o;
            o.x = pk2(acc[4*g+0] + b1v[4*g+0], acc[4*g+1] + b1v[4*g+1]);
            o.y = pk2(acc[4*g+2] + b1v[4*g+2], acc[4*g+3] + b1v[4*g+3]);
            *(uint2*)(EB + l31 * PST + cb) = o;
        }
        __syncthreads();   // B1: EB writes visible (prev EB readers done via prev B2)

        // (4) coalesced store: 16 consecutive lanes emit one 256 B output row.
        #pragma unroll
        for (int i = 0; i < 2; ++i) {
            const int f = i * 256 + tid;
            const int r = f >> 4;
            const int c = f & 15;
            const int s2 = t * PTR + r;
            if (s2 < N)
                *(uint4v*)(O + (long long)s2 * HID + c * 8) =
                    *(const uint4v*)(EB + r * PST + c * 8);
        }

        // (5) write-late staging: vmcnt wait covers only residual latency.
        if (pf) stage_write(zl[p ^ 1]);

        __syncthreads();   // B2: zl[p^1] staged; EB reads done before next epilogue
        p ^= 1;
        t = tn;
    }
}

// ---------------- Phase 2: out[e] = w2 . relu(U[row[e]] + V[col[e]]) + b2
// 16 lanes/edge-group, 4 edges per group (8 gathers of 16 B in flight/thread).
__global__ __launch_bounds__(256)
void edge_kernel(const unsigned short* __restrict__ U,   // [NS,128] bf16
                 const unsigned short* __restrict__ V,   // [NT,128] bf16
                 const int*   __restrict__ row, const int* __restrict__ col,
                 const float* __restrict__ w2, const float* __restrict__ b2,
                 float* __restrict__ out, int E)
{
    const int tid = threadIdx.x;
    const int g   = tid >> 4;        // group 0..15
    const int c16 = tid & 15;        // channel chunk (8 channels)

    const long long eb = (long long)blockIdx.x * 64 + g * 4;

    int ri[4], ci[4];
    #pragma unroll
    for (int j = 0; j < 4; ++j) {
        long long e = eb + j;
        if (e >= E) e = E - 1;
        ri[j] = row[e]; ci[j] = col[e];
    }
    bf16x8 u[4], v[4];
    #pragma unroll
    for (int j = 0; j < 4; ++j) {
        u[j] = *(const bf16x8*)(U + (long long)ri[j] * HID + c16 * 8);
        v[j] = *(const bf16x8*)(V + (long long)ci[j] * HID + c16 * 8);
    }

    const float4 wa = *(const float4*)(w2 + c16 * 8);
    const float4 wb = *(const float4*)(w2 + c16 * 8 + 4);
    const float w2v[8] = {wa.x, wa.y, wa.z, wa.w, wb.x, wb.y, wb.z, wb.w};

    float p[4] = {0.0f, 0.0f, 0.0f, 0.0f};
    #pragma unroll
    for (int j = 0; j < 4; ++j) {
        #pragma unroll
        for (int k = 0; k < 8; ++k) {
            const float h = fmaxf(bf2f((unsigned short)u[j][k]) +
                                  bf2f((unsigned short)v[j][k]), 0.0f);
            p[j] = fmaf(h, w2v[k], p[j]);
        }
    }
    #pragma unroll
    for (int d = 1; d < 16; d <<= 1) {
        #pragma unroll
        for (int j = 0; j < 4; ++j) p[j] += __shfl_xor(p[j], d, 64);
    }
    if (c16 == 0) {
        const float bb = b2[0];
        if (eb + 3 < E) {
            *(float4*)(out + eb) = make_float4(p[0] + bb, p[1] + bb, p[2] + bb, p[3] + bb);
        } else {
            #pragma unroll
            for (int j = 0; j < 4; ++j)
                if (eb + j < E) out[eb + j] = p[j] + bb;
        }
    }
}

// ---------------- Fallback: round-2 proven fused kernel (only if ws too small)
__global__ __launch_bounds__(256, 2)
void edge_mlp_fused(const float* __restrict__ z_sotu, const float* __restrict__ z_taxon,
                    const int* __restrict__ row, const int* __restrict__ col,
                    const float* __restrict__ w1, const float* __restrict__ b1,
                    const float* __restrict__ w2, const float* __restrict__ b2,
                    float* __restrict__ out, int E)
{
    __shared__ __align__(16) unsigned short zsh[FTE * 256];
    const int tid  = threadIdx.x;
    const int wave = tid >> 6;
    const int lane = tid & 63;
    const int l31  = lane & 31;
    const int hlf  = lane >> 5;
    const long long e0 = (long long)blockIdx.x * FTE;
    {
        const int ch  = lane & 15;
        const int rhl = lane >> 4;
        #pragma unroll
        for (int pass = 0; pass < 16; ++pass) {
            const int rh = pass * 4 + rhl;
            const int r  = 32 * wave + (rh >> 1);
            const int hh = rh & 1;
            long long e = e0 + r;
            if (e >= E) e = E - 1;
            const int idx = hh ? col[e] : row[e];
            const float* src = (hh ? z_taxon : z_sotu) + (long long)idx * HID + ch * 8;
            const float4 a = *(const float4*)(src);
            const float4 b = *(const float4*)(src + 4);
            const int c = hh * 16 + ch;
            const int q = c ^ (r & 31);
            *(bf16x8*)(zsh + r * 256 + q * 8) = pack8(a, b);
        }
    }
    bf16x8 afrag[16];
    {
        const float* wrow = w1 + (32 * wave + l31) * 256 + hlf * 8;
        #pragma unroll
        for (int ks = 0; ks < 16; ++ks) {
            const float4 a = *(const float4*)(wrow + ks * 16);
            const float4 b = *(const float4*)(wrow + ks * 16 + 4);
            afrag[ks] = pack8(a, b);
        }
    }
    __syncthreads();
    f32x16 acc[4] = {};
    #pragma unroll
    for (int ks = 0; ks < 16; ++ks) {
        #pragma unroll
        for (int nt = 0; nt < 4; ++nt) {
            const int el = 32 * nt + l31;
            const int q  = (2 * ks + hlf) ^ l31;
            bf16x8 bfrag = *(const bf16x8*)(zsh + el * 256 + q * 8);
            acc[nt] = __builtin_amdgcn_mfma_f32_32x32x16_bf16(afrag[ks], bfrag, acc[nt], 0, 0, 0);
        }
    }
    __syncthreads();
    float* partial = (float*)zsh;
    float b1v[16], w2v[16];
    #pragma unroll
    for (int g = 0; g < 4; ++g) {
        const int hb = 32 * wave + 8 * g + 4 * hlf;
        const float4 bb = *(const float4*)(b1 + hb);
        const float4 ww = *(const float4*)(w2 + hb);
        b1v[4*g+0] = bb.x; b1v[4*g+1] = bb.y; b1v[4*g+2] = bb.z; b1v[4*g+3] = bb.w;
        w2v[4*g+0] = ww.x; w2v[4*g+1] = ww.y; w2v[4*g+2] = ww.z; w2v[4*g+3] = ww.w;
    }
    #pragma unroll
    for (int nt = 0; nt < 4; ++nt) {
        float p = 0.0f;
        #pragma unroll
        for (int r = 0; r < 16; ++r) {
            const float h = fmaxf(acc[nt][r] + b1v[r], 0.0f);
            p = fmaf(h, w2v[r], p);
        }
        p += __shfl_xor(p, 32, 64);
        if (hlf == 0)
            partial[wave * FTE + 32 * nt + l31] = p;
    }
    __syncthreads();
    if (tid < FTE) {
        const long long e = e0 + tid;
        if (e < E) {
            out[e] = partial[0 * FTE + tid] + partial[1 * FTE + tid]
                   + partial[2 * FTE + tid] + partial[3 * FTE + tid]
                   + b2[0];
        }
    }
}

extern "C" void kernel_launch(void* const* d_in, const int* in_sizes, int n_in,
                              void* d_out, int out_size, void* d_ws, size_t ws_size,
                              hipStream_t stream) {
    const float* z_sotu  = (const float*)d_in[0];
    const float* z_taxon = (const float*)d_in[1];
    const int*   row     = (const int*)d_in[2];
    const int*   col     = (const int*)d_in[3];
    const float* w1      = (const float*)d_in[4];
    const float* b1      = (const float*)d_in[5];
    const float* w2      = (const float*)d_in[6];
    const float* b2      = (const float*)d_in[7];
    float*       out     = (float*)d_out;

    const int NS = in_sizes[0] / HID;   // 100000
    const int NT = in_sizes[1] / HID;   //  50000
    const int E  = in_sizes[2];
    // U (25.6 MB) + V (12.8 MB) + WF fragment buffer (64 KB)
    const size_t need = ((size_t)NS + NT) * HID * 2 + 65536;

    if (ws_size >= need) {
        unsigned short* U  = (unsigned short*)d_ws;
        unsigned short* Vv = U + (size_t)NS * HID;
        unsigned short* WF = Vv + (size_t)NT * HID;
        hipLaunchKernelGGL(w1prep_kernel, dim3(16), dim3(256), 0, stream, w1, WF);
        hipLaunchKernelGGL(prep_kernel, dim3(GU + GT), dim3(256), 0, stream,
                           z_sotu, z_taxon, WF, b1, U, Vv, NS, NT);
        const int nblocks = (E + 63) / 64;
        hipLaunchKernelGGL(edge_kernel, dim3(nblocks), dim3(256), 0, stream,
                           U, Vv, row, col, w2, b2, out, E);
    } else {
        const int nblocks = (E + FTE - 1) / FTE;
        hipLaunchKernelGGL(edge_mlp_fused, dim3(nblocks), dim3(256), 0, stream,
                           z_sotu, z_taxon, row, col, w1, b1, w2, b2, out, E);
    }
}